// Round 16
// baseline (1584.087 us; speedup 1.0000x reference)
//
#include <hip/hip_runtime.h>

typedef __bf16 bf16x8 __attribute__((ext_vector_type(8)));
typedef float fx4 __attribute__((ext_vector_type(4)));
typedef unsigned short u16x8 __attribute__((ext_vector_type(8)));
typedef unsigned short u16x4 __attribute__((ext_vector_type(4)));

__device__ __forceinline__ unsigned short f2b(float f) {
  unsigned u = __float_as_uint(f);
  u = (u + 0x7fffu + ((u >> 16) & 1u)) >> 16;
  return (unsigned short)u;
}
__device__ __forceinline__ float b2f(unsigned short s) {
  return __uint_as_float((unsigned)s << 16);
}

__device__ __forceinline__ void gload16(const void* g, void* l) {
  __builtin_amdgcn_global_load_lds(
      (const __attribute__((address_space(1))) unsigned int*)g,
      (__attribute__((address_space(3))) unsigned int*)l, 16, 0, 0);
}

// ---------------------------------------------------------------------------
// 128x128-tile bf16 MFMA GEMM, XCD-chunked block swizzle.
// MODE 1 (G1'): rows = dest-sorted edges, K=256. A = eas[s]. zxb tile split
//   into two COLUMN-CONTIGUOUS 16 KB halves (cols [h*64,(h+1)*64) = one full
//   128B line per row per half): half-0 staged in the prologue, half-1 issued
//   after round-0's CL sync (hides under round-0 merge). Epilogue rounds are
//   split by wc-half: round h writes output cols [h*64,h*64+64) -- interior
//   run stores are contiguous 256B (no partial-line double-write), each zxb
//   line fetched exactly once. LDS 34.8 KB, __launch_bounds__(256,4).
//   Run merge: ballot-compacted; interior runs plain-store into aggH[dest],
//   boundary runs atomicAdd (rows pre-zeroed by zb_k/zc_k).
// MODE 2 (A2): manual ds_write staging -> legacy __syncthreads loop.
// MODE 3 (G3): A = concat [xb|agg2b] via gload16; +b3, leaky -> H3 bf16
// MODE 4 (G4): A = H3 via gload16; +b4 -> fp32 out
// MODE 5 (ZX): A = xb via gload16; plain bf16 store -> zxb
// Modes 3/4/5: T4 counted-vmcnt 2-phase loop (R14).
// Bt is [N][K] bf16 pre-transposed. grid = mtc*8*NT (1-D).
// ---------------------------------------------------------------------------
template<int MODE, int K, int N, int NT, bool EAB>
__global__ __launch_bounds__(256, (MODE == 1) ? 4 : 1)
void gemm_k(const unsigned short* __restrict__ A,        // mode4: H3
            const unsigned short* __restrict__ xb,       // bf16 x
            const unsigned short* __restrict__ eas,      // bf16 sorted edge_attr
            const float* __restrict__ eaf,               // fp32 edge_attr
            const float* __restrict__ aggH_in,           // mode2 A source
            const float* __restrict__ cnt,
            const unsigned short* __restrict__ agg2b_in, // mode3 A source k>=256
            const unsigned short* __restrict__ zxb,      // mode1 LDS-staged gather
            const int* __restrict__ perm,                // sorted->orig edge
            const int* __restrict__ ssrc,                // sorted src node
            const int* __restrict__ sdst,                // sorted dest node
            const unsigned short* __restrict__ Bt,
            const float* __restrict__ bias,
            float* __restrict__ outf,                    // mode1: aggH ; mode4: out
            unsigned short* __restrict__ outb,           // mode2/3/5 bf16 out
            int M, int base, int mt, int mtc)
{
  // XCD-chunked swizzle: NT n-tiles of one tile_m run consecutively on one XCD.
  const int bid = blockIdx.x;
  const int xcd = bid & 7;
  const int sl  = bid >> 3;
  const int tile_n = sl % NT;
  const int tile_m = xcd * mtc + sl / NT;
  if (tile_m >= mt) return;
  const int mbase = tile_m * 128;

  // smem layout:
  //  MODE 1: [0,8192) Al | [8192,16384) Bl | CL [128][66] bf16 in [0,16896)
  //          [16896,33280) ZLh [128][64] bf16 (column-contiguous half)
  //          [33280,34816) runs_s/e/d | [34816,34832) wmask
  //  MODE 2: single buffer 16 KB
  //  else  : double buffer  [0,16384) buf0 (Al|Bl) | [16384,32768) buf1
  constexpr int SMEM = (MODE == 1) ? 34832 : ((MODE == 2) ? 16384 : 32768);
  __shared__ __align__(16) char smem[SMEM];

  const int t = threadIdx.x;
  const int w = t >> 6, l = t & 63;
  const int wr = w >> 1, wc = w & 1;
  const int lr = l & 15, lk = l >> 4;

  fx4 zero = {0.f, 0.f, 0.f, 0.f};
  fx4 acc[4][4];
#pragma unroll
  for (int i = 0; i < 4; i++)
#pragma unroll
    for (int j = 0; j < 4; j++) acc[i][j] = zero;

  // Stage one 128x32 A-tile + 128x32 B-tile into buffer b.
  auto STAGE = [&](int ks, int b) {
    const int k0 = ks * 32;
    char* Ab = (char*)smem + b * 16384;
    char* Bb = Ab + 8192;
#pragma unroll
    for (int it = 0; it < 2; ++it) {
      const int c = t + it * 256;          // 16B chunk id 0..511
      const int row = c >> 2, u = c & 3;
      gload16(Bt + (size_t)(tile_n * 128 + row) * K + (k0 + u * 8),
              Bb + c * 16);
      int rl = mbase + row; if (rl >= M) rl = M - 1;
      if constexpr (MODE == 1) {
        if constexpr (EAB) {
          gload16(eas + (size_t)rl * 256 + (k0 + u * 8), Ab + c * 16);
        } else {
          const int e = perm[rl];
          const float* s = eaf + (size_t)e * 256 + (k0 + u * 8);
          fx4 f0 = *(const fx4*)s, f1 = *(const fx4*)(s + 4);
          u16x8 v;
          v[0]=f2b(f0[0]); v[1]=f2b(f0[1]); v[2]=f2b(f0[2]); v[3]=f2b(f0[3]);
          v[4]=f2b(f1[0]); v[5]=f2b(f1[1]); v[6]=f2b(f1[2]); v[7]=f2b(f1[3]);
          *(u16x8*)(Ab + c * 16) = v;
        }
      } else if constexpr (MODE == 2) {
        const float ct = cnt[rl];
        const float rs = 1.f / fmaxf(ct, 1.f);
        const float* s = aggH_in + (size_t)rl * 1024 + (k0 + u * 8);
        fx4 f0 = *(const fx4*)s, f1 = *(const fx4*)(s + 4);
        u16x8 v;
        v[0]=f2b(f0[0]*rs); v[1]=f2b(f0[1]*rs); v[2]=f2b(f0[2]*rs); v[3]=f2b(f0[3]*rs);
        v[4]=f2b(f1[0]*rs); v[5]=f2b(f1[1]*rs); v[6]=f2b(f1[2]*rs); v[7]=f2b(f1[3]*rs);
        *(u16x8*)(Ab + c * 16) = v;
      } else if constexpr (MODE == 3) {
        const int node = base + rl;
        if (k0 < 256)
          gload16(xb + (size_t)node * 256 + (k0 + u * 8), Ab + c * 16);
        else
          gload16(agg2b_in + (size_t)node * 512 + (k0 - 256) + u * 8,
                  Ab + c * 16);
      } else if constexpr (MODE == 5) {
        gload16(xb + (size_t)rl * 256 + (k0 + u * 8), Ab + c * 16);
      } else {
        gload16(A + (size_t)rl * K + (k0 + u * 8), Ab + c * 16);
      }
    }
  };

  auto COMPUTE = [&](int b) {
    const unsigned short* Al = (const unsigned short*)((char*)smem + b * 16384);
    const unsigned short* Bl = Al + 4096;
    bf16x8 af[4], bfr[4];
    const int mb0 = wr * 64, nb0 = wc * 64;
#pragma unroll
    for (int i = 0; i < 4; i++)
      af[i] = *(const bf16x8*)(Al + (mb0 + i * 16 + lr) * 32 + lk * 8);
#pragma unroll
    for (int j = 0; j < 4; j++)
      bfr[j] = *(const bf16x8*)(Bl + (nb0 + j * 16 + lr) * 32 + lk * 8);
#pragma unroll
    for (int i = 0; i < 4; i++)
#pragma unroll
      for (int j = 0; j < 4; j++)
        acc[i][j] = __builtin_amdgcn_mfma_f32_16x16x32_bf16(af[i], bfr[j],
                                                            acc[i][j], 0, 0, 0);
  };

  // ZL half-tile gather: half h = cols [h*64,(h+1)*64) -- ONE 128B line per
  // row, fetched exactly once. ZLh_u16[row*64 + q] = zxb col (tn*128+h*64+q).
  auto ZSTAGE = [&](int h) {
#pragma unroll
    for (int q2 = 0; q2 < 4; ++q2) {
      const int c = q2 * 256 + t;          // 0..1023
      const int zrow = c >> 3, u = c & 7;
      int gr = mbase + zrow; if (gr >= M) gr = M - 1;
      gload16(zxb + (size_t)ssrc[gr] * 1024 + tile_n * 128 + h * 64 + u * 8,
              (char*)smem + 16896 + c * 16);
    }
  };

  const int NK = K / 32;
  if constexpr (MODE == 1) {
    ZSTAGE(0);   // half-0: drained by the first K-loop barrier
    for (int ks = 0; ks < NK; ++ks) {
      STAGE(ks, 0);
      __syncthreads();
      COMPUTE(0);
      __syncthreads();
    }
  } else if constexpr (MODE == 2) {
    for (int ks = 0; ks < NK; ++ks) {
      STAGE(ks, 0);
      __syncthreads();
      COMPUTE(0);
      __syncthreads();
    }
  } else {
    // T4 counted-vmcnt 2-phase loop [R14]
    STAGE(0, 0);
    for (int ks = 0; ks < NK; ++ks) {
      const int cur = ks & 1;
      if (ks + 1 < NK) {
        STAGE(ks + 1, cur ^ 1);
        asm volatile("s_waitcnt vmcnt(4)" ::: "memory");
      } else {
        asm volatile("s_waitcnt vmcnt(0)" ::: "memory");
      }
      __builtin_amdgcn_s_barrier();
      COMPUTE(cur);
      __builtin_amdgcn_s_barrier();
    }
  }

  // Epilogue. C/D layout: col = lane&15, row = (lane>>4)*4 + reg  [m89]
  if constexpr (MODE == 1) {
    // ---- ballot-compacted run merge; 2 rounds, each a contiguous 64-col
    //      half (round h handled by wc==h threads' acc) ----
    int rows = M - mbase; if (rows > 128) rows = 128;
    unsigned short* CL = (unsigned short*)smem;       // [128][66] u16, 16896 B
    unsigned short* ZLh = (unsigned short*)(smem + 16896); // [128][64] u16
    int* runs_s = (int*)(smem + 33280);               // 128
    int* runs_e = (int*)(smem + 33792);               // 128
    int* runs_d = (int*)(smem + 34304);               // 128
    unsigned long long* wmask = (unsigned long long*)(smem + 34816); // 2
    int flag = 0;
    if (t < 128)
      flag = (t < rows) && ((t == 0) || (sdst[mbase + t] != sdst[mbase + t - 1]));
    unsigned long long bm = __ballot(flag);
    if (l == 0 && w < 2) wmask[w] = bm;
    __syncthreads();
    const unsigned long long m0 = wmask[0], m1 = wmask[1];
    const int nruns = __builtin_popcountll(m0) + __builtin_popcountll(m1);
    if (flag) {
      int rank, rend;
      if (t < 64) {
        rank = __builtin_popcountll(m0 & ((t == 0) ? 0ull : ((1ull << t) - 1)));
        unsigned long long above = (t == 63) ? 0ull : (m0 & (~0ull << (t + 1)));
        if (above) rend = __builtin_ctzll(above);
        else if (m1) rend = 64 + __builtin_ctzll(m1);
        else rend = rows;
      } else {
        const int tt = t - 64;
        rank = __builtin_popcountll(m0) +
               __builtin_popcountll(m1 & ((tt == 0) ? 0ull : ((1ull << tt) - 1)));
        unsigned long long above = (tt == 63) ? 0ull : (m1 & (~0ull << (tt + 1)));
        rend = above ? 64 + __builtin_ctzll(above) : rows;
      }
      runs_s[rank] = t; runs_e[rank] = rend; runs_d[rank] = sdst[mbase + t];
    }
    for (int h = 0; h < 2; ++h) {
      if (wc == h) {
        // this half's acc columns: n = tile_n*128 + h*64 + j*16 + lr
#pragma unroll
        for (int j = 0; j < 4; ++j) {
          const float bj = bias[tile_n * 128 + h * 64 + j * 16 + lr];
          const int q = j * 16 + lr;            // col within half (0..63)
#pragma unroll
          for (int i = 0; i < 4; i++)
#pragma unroll
            for (int r = 0; r < 4; r++) {
              const int lrow = wr * 64 + i * 16 + lk * 4 + r;
              float v = acc[i][j][r] + bj + b2f(ZLh[lrow * 64 + q]);
              v = v >= 0.f ? v : 0.01f * v;
              CL[lrow * 66 + q] = f2b(v);
            }
        }
      }
      __syncthreads();                 // CL ready; all ZLh(half h) reads done
      if (h == 0) ZSTAGE(1);           // half-1 gather hides under merge below
      for (int task = t; task < nruns * 64; task += 256) {
        const int ri = task >> 6, c = task & 63;
        const int rs = runs_s[ri], re = runs_e[ri];
        float s = 0.f;
        for (int r = rs; r < re; ++r) s += b2f(CL[r * 66 + c]);
        const int n = tile_n * 128 + h * 64 + c;
        float* addr = outf + (size_t)runs_d[ri] * 1024 + n;
        const bool open = (rs == 0 && mbase > 0) || (re == rows && mbase + rows < M);
        if (open) atomicAdd(addr, s); else *addr = s;
      }
      __syncthreads();                 // drains half-1 gather before round 1
    }
  } else {
#pragma unroll
    for (int j = 0; j < 4; j++) {
      const int n = tile_n * 128 + wc * 64 + j * 16 + lr;
      float bj = 0.f;
      if constexpr (MODE == 2 || MODE == 3 || MODE == 4) bj = bias[n];
#pragma unroll
      for (int i = 0; i < 4; i++) {
        const int m0 = mbase + wr * 64 + i * 16 + lk * 4;
#pragma unroll
        for (int r = 0; r < 4; r++) {
          const int m = m0 + r;
          if (m < M) {
            float v = acc[i][j][r];
            if constexpr (MODE == 2) {
              v += (cnt[m] > 0.f ? bj : 0.f);
              outb[(size_t)m * N + n] = f2b(v);
            } else if constexpr (MODE == 3) {
              v += bj;
              v = v >= 0.f ? v : 0.01f * v;
              outb[(size_t)m * N + n] = f2b(v);
            } else if constexpr (MODE == 5) {
              outb[(size_t)m * N + n] = f2b(v);
            } else {
              outf[(size_t)(base + m) * N + n] = v + bj;
            }
          }
        }
      }
    }
  }
}

// ---------------------------------------------------------------------------
// Helper kernels
// ---------------------------------------------------------------------------
__global__ void fix_idx_k(const int* __restrict__ src, int* __restrict__ dst, int n2) {
  int i = blockIdx.x * blockDim.x + threadIdx.x;
  if (i >= n2) return;
  bool is64 = true;
#pragma unroll
  for (int p = 0; p < 16; ++p) is64 = is64 && (src[2 * p + 1] == 0);
  dst[i] = is64 ? src[2 * i] : src[i];
}

__global__ void cvt_f2b_k(const float* __restrict__ x, unsigned short* __restrict__ o,
                          long n4) {
  long i = (long)blockIdx.x * blockDim.x + threadIdx.x;
  if (i < n4) {
    fx4 f = *(const fx4*)(x + i * 4);
    u16x4 v; v[0]=f2b(f[0]); v[1]=f2b(f[1]); v[2]=f2b(f[2]); v[3]=f2b(f[3]);
    *(u16x4*)(o + i * 4) = v;
  }
}

// eas[s][0:256] = bf16(ea[perm[s]][0:256])  (gather rows into sorted order)
__global__ void cvt_eas_k(const float* __restrict__ ea, const int* __restrict__ perm,
                          unsigned short* __restrict__ eas, int E) {
  long i = (long)blockIdx.x * blockDim.x + threadIdx.x;
  if (i >= (long)E * 64) return;
  const int s = (int)(i >> 6), q = (int)(i & 63);
  const float* src = ea + (size_t)perm[s] * 256 + q * 4;
  fx4 f = *(const fx4*)src;
  u16x4 v; v[0]=f2b(f[0]); v[1]=f2b(f[1]); v[2]=f2b(f[2]); v[3]=f2b(f[3]);
  *(u16x4*)(eas + (size_t)s * 256 + q * 4) = v;
}

// W[K][N] fp32 -> Wt[N][K] bf16
__global__ void cvt_w_k(const float* __restrict__ W, unsigned short* __restrict__ Wt,
                        int K, int N) {
  long i = (long)blockIdx.x * blockDim.x + threadIdx.x;
  if (i < (long)K * N) {
    int k = (int)(i / N), n = (int)(i % N);
    Wt[(size_t)n * K + k] = f2b(W[i]);
  }
}

__global__ void cnt_kk(const int* __restrict__ ecol, float* __restrict__ cnt, int E) {
  int i = blockIdx.x * blockDim.x + threadIdx.x;
  if (i < E) atomicAdd(cnt + ecol[i], 1.f);
}

// zero rows of aggH that will receive atomicAdd: first/last run dest per tile
__global__ void zb_k(const int* __restrict__ sdst, float* __restrict__ aggH,
                     int M, int mt) {
  const int b = blockIdx.x;            // 0..2*mt-1
  int row = (b >> 1) * 128 + ((b & 1) ? 127 : 0);
  if (row >= M) row = M - 1;
  const int dest = sdst[row];
  fx4 z = {0.f, 0.f, 0.f, 0.f};
  *(fx4*)(aggH + (size_t)dest * 1024 + threadIdx.x * 4) = z;
}

// zero rows of aggH for nodes with no incoming edges (never written by G1')
__global__ void zc_k(const float* __restrict__ cnt, float* __restrict__ aggH,
                     int Nn) {
  const int nidx = blockIdx.x;
  if (nidx >= Nn || cnt[nidx] != 0.f) return;
  fx4 z = {0.f, 0.f, 0.f, 0.f};
  *(fx4*)(aggH + (size_t)nidx * 1024 + threadIdx.x * 4) = z;
}

// Single-block exclusive scan of (int)cnt -> pos  (Hillis-Steele per chunk)
__global__ __launch_bounds__(1024)
void scan_k(const float* __restrict__ cnt, int* __restrict__ pos, int Nn) {
  __shared__ int sdata[1024];
  __shared__ int carry;
  if (threadIdx.x == 0) carry = 0;
  __syncthreads();
  for (int bb = 0; bb < Nn; bb += 1024) {
    const int i = bb + threadIdx.x;
    const int v = (i < Nn) ? (int)cnt[i] : 0;
    sdata[threadIdx.x] = v;
    __syncthreads();
    for (int off = 1; off < 1024; off <<= 1) {
      int tv = (threadIdx.x >= off) ? sdata[threadIdx.x - off] : 0;
      __syncthreads();
      sdata[threadIdx.x] += tv;
      __syncthreads();
    }
    const int excl = sdata[threadIdx.x] - v + carry;
    if (i < Nn) pos[i] = excl;
    __syncthreads();
    if (threadIdx.x == 1023) carry += sdata[1023];
    __syncthreads();
  }
}

// counting-sort scatter: perm (sorted->orig), ssrc, sdst
__global__ void perm_k(const int* __restrict__ idx, int E, int* __restrict__ pos,
                       int* __restrict__ perm, int* __restrict__ ssrc,
                       int* __restrict__ sdst) {
  int e = blockIdx.x * blockDim.x + threadIdx.x;
  if (e >= E) return;
  const int d = idx[E + e];
  const int s = atomicAdd(pos + d, 1);
  perm[s] = e;
  ssrc[s] = idx[e];
  sdst[s] = d;
}

// ---------------------------------------------------------------------------
extern "C" void kernel_launch(void* const* d_in, const int* in_sizes, int n_in,
                              void* d_out, int out_size, void* d_ws, size_t ws_size,
                              hipStream_t stream)
{
  const float* x  = (const float*)d_in[0];
  const int* eraw = (const int*)d_in[1];
  const float* ea = (const float*)d_in[2];
  const float* W1 = (const float*)d_in[5];
  const float* b1 = (const float*)d_in[6];
  const float* W2 = (const float*)d_in[7];
  const float* b2 = (const float*)d_in[8];
  const float* W3 = (const float*)d_in[9];
  const float* b3 = (const float*)d_in[10];
  const float* W4 = (const float*)d_in[11];
  const float* b4 = (const float*)d_in[12];
  float* out = (float*)d_out;

  const int Nn = in_sizes[0] / 256;   // 50000
  const int E  = in_sizes[1] / 2;     // 500000

  // ---- workspace carve (256B-aligned bump allocator) ----
  char* p = (char*)d_ws;
  auto take = [&](size_t bytes) -> char* {
    char* r = p; p += (bytes + 255) & ~(size_t)255; return r;
  };
  unsigned short* W1xt = (unsigned short*)take((size_t)1024 * 256 * 2);
  unsigned short* W1et = (unsigned short*)take((size_t)1024 * 256 * 2);
  unsigned short* W2t  = (unsigned short*)take((size_t)1024 * 512 * 2);
  unsigned short* W3t  = (unsigned short*)take((size_t)768 * 1536 * 2);
  unsigned short* W4t  = (unsigned short*)take((size_t)1536 * 256 * 2);
  int* idx  = (int*)take((size_t)2 * E * 4);
  float* cnt  = (float*)take((size_t)Nn * 4);
  float* aggH = (float*)take((size_t)Nn * 1024 * 4);      // layer-1 scatter-sum
  unsigned short* agg2b = (unsigned short*)take((size_t)Nn * 512 * 2);
  unsigned short* xb    = (unsigned short*)take((size_t)Nn * 256 * 2);
  unsigned short* zxb   = (unsigned short*)take((size_t)Nn * 1024 * 2);
  int* pos  = (int*)take((size_t)Nn * 4);
  int* perm = (int*)take((size_t)E * 4);
  int* ssrc = (int*)take((size_t)E * 4);
  int* sdst = (int*)take((size_t)E * 4);

  long avail = (long)ws_size - (long)(p - (char*)d_ws);

  unsigned short* eas = nullptr;              // sorted bf16 edge_attr (optional)
  const long eas_bytes = (((long)E * 256 * 2) + 255) & ~255L;
  if (avail >= eas_bytes + 128 * 3072 + 1024) {
    eas = (unsigned short*)take((size_t)E * 256 * 2);
    avail -= eas_bytes;
  }
  long bandN = avail / 3072;  bandN &= ~127L;
  if (bandN > 50048) bandN = 50048;
  if (bandN < 128)   bandN = 128;
  unsigned short* H3 = (unsigned short*)take((size_t)bandN * 3072);

  const int mtE = (E + 127) / 128;

  hipMemsetAsync(cnt, 0, (size_t)Nn * 4, stream);
  fix_idx_k<<<(2 * E + 255) / 256, 256, 0, stream>>>(eraw, idx, 2 * E);
  cnt_kk<<<(E + 255) / 256, 256, 0, stream>>>(idx + E, cnt, E);   // dest counts
  scan_k<<<1, 1024, 0, stream>>>(cnt, pos, Nn);
  perm_k<<<(E + 255) / 256, 256, 0, stream>>>(idx, E, pos, perm, ssrc, sdst);
  // targeted zeroing of atomicAdd-target rows (replaces 205 MB memset)
  zb_k<<<mtE * 2, 256, 0, stream>>>(sdst, aggH, E, mtE);
  zc_k<<<Nn, 256, 0, stream>>>(cnt, aggH, Nn);
  cvt_f2b_k<<<(Nn * 64 + 255) / 256, 256, 0, stream>>>(x, xb, (long)Nn * 64);
  if (eas)
    cvt_eas_k<<<(int)(((long)E * 64 + 255) / 256), 256, 0, stream>>>(ea, perm,
                                                                     eas, E);
  cvt_w_k<<<(256 * 1024 + 255) / 256, 256, 0, stream>>>(W1, W1xt, 256, 1024);
  cvt_w_k<<<(256 * 1024 + 255) / 256, 256, 0, stream>>>(W1 + 256 * 1024, W1et,
                                                        256, 1024);
  cvt_w_k<<<(1024 * 512 + 255) / 256, 256, 0, stream>>>(W2, W2t, 1024, 512);
  cvt_w_k<<<(768 * 1536 + 255) / 256, 256, 0, stream>>>(W3, W3t, 768, 1536);
  cvt_w_k<<<(1536 * 256 + 255) / 256, 256, 0, stream>>>(W4, W4t, 1536, 256);

  // ZX: zxb = bf16(x @ W1x)   [x-half of layer 1, deduped to nodes]
  {
    const int mt = (Nn + 127) / 128, mtc = (mt + 7) / 8;
    gemm_k<5, 256, 1024, 8, false><<<mtc * 8 * 8, 256, 0, stream>>>(
        nullptr, xb, nullptr, nullptr, nullptr, nullptr, nullptr, nullptr,
        nullptr, nullptr, nullptr, W1xt, nullptr, nullptr, zxb, Nn, 0, mt, mtc);
  }

  // G1': edge layer-1 (ea half, K=256) + contiguous split-ZL + run-merge
  {
    const int mt = mtE, mtc = (mt + 7) / 8;
    const int grid = mtc * 8 * 8;
    if (eas)
      gemm_k<1, 256, 1024, 8, true><<<grid, 256, 0, stream>>>(
          nullptr, nullptr, eas, ea, nullptr, nullptr, nullptr, zxb, perm,
          ssrc, sdst, W1et, b1, aggH, nullptr, E, 0, mt, mtc);
    else
      gemm_k<1, 256, 1024, 8, false><<<grid, 256, 0, stream>>>(
          nullptr, nullptr, nullptr, ea, nullptr, nullptr, nullptr, zxb, perm,
          ssrc, sdst, W1et, b1, aggH, nullptr, E, 0, mt, mtc);
  }

  // A2: agg2 = (aggH/max(cnt,1)) @ W2 + (cnt>0)*b2   [hoisted layer 2]
  {
    const int mt = (Nn + 127) / 128, mtc = (mt + 7) / 8;
    gemm_k<2, 1024, 512, 4, false><<<mtc * 8 * 4, 256, 0, stream>>>(
        nullptr, nullptr, nullptr, nullptr, aggH, cnt, nullptr, nullptr,
        nullptr, nullptr, nullptr, W2t, b2, nullptr, agg2b, Nn, 0, mt, mtc);
  }

  // node MLP, banded over nodes
  for (long base = 0; base < Nn; base += bandN) {
    long rem = Nn - base;
    int mb = (int)(rem < bandN ? rem : bandN);
    int mt = (mb + 127) / 128, mtc = (mt + 7) / 8;
    gemm_k<3, 768, 1536, 12, false><<<mtc * 8 * 12, 256, 0, stream>>>(
        nullptr, xb, nullptr, nullptr, nullptr, nullptr, agg2b, nullptr,
        nullptr, nullptr, nullptr, W3t, b3, nullptr, H3, mb, (int)base, mt, mtc);
    gemm_k<4, 1536, 256, 2, false><<<mtc * 8 * 2, 256, 0, stream>>>(
        H3, nullptr, nullptr, nullptr, nullptr, nullptr, nullptr, nullptr,
        nullptr, nullptr, nullptr, W4t, b4, out, nullptr, mb, (int)base, mt, mtc);
  }
}

// Round 17
// 1571.057 us; speedup vs baseline: 1.0083x; 1.0083x over previous
//
#include <hip/hip_runtime.h>

typedef __bf16 bf16x8 __attribute__((ext_vector_type(8)));
typedef float fx4 __attribute__((ext_vector_type(4)));
typedef unsigned short u16x8 __attribute__((ext_vector_type(8)));
typedef unsigned short u16x4 __attribute__((ext_vector_type(4)));

__device__ __forceinline__ unsigned short f2b(float f) {
  unsigned u = __float_as_uint(f);
  u = (u + 0x7fffu + ((u >> 16) & 1u)) >> 16;
  return (unsigned short)u;
}
__device__ __forceinline__ float b2f(unsigned short s) {
  return __uint_as_float((unsigned)s << 16);
}

__device__ __forceinline__ void gload16(const void* g, void* l) {
  __builtin_amdgcn_global_load_lds(
      (const __attribute__((address_space(1))) unsigned int*)g,
      (__attribute__((address_space(3))) unsigned int*)l, 16, 0, 0);
}

// ---------------------------------------------------------------------------
// 128x128-tile bf16 MFMA GEMM, XCD-chunked block swizzle.  [R15 structure]
// MODE 1 (G1'): rows = dest-sorted edges, K=256. A = eas[s]. zxb tile split
//   into two 16 KB halves: half-0 staged in prologue, half-1 issued after
//   round-0's CL sync (hides under round-0 merge). LDS 34.8 KB,
//   __launch_bounds__(256,4). Epilogue: v = acc + b1[n] + ZLh, leaky ->
//   bf16 CL [128][66]; 2-round ballot-compacted run merge; interior runs
//   plain-store into aggH[dest], boundary runs atomicAdd (rows pre-zeroed).
// MODE 2 (A2): A = bf16(aggH[node]) (normalize moved to EPILOGUE: /max(cnt,1)
//   + (cnt>0)*b2) -> agg2b bf16.  Legacy __syncthreads loop.
// MODE 3 (G3): A = concat [xb|agg2b] via gload16; +b3, leaky -> H3 bf16
// MODE 4 (G4): A = H3 via gload16; +b4 -> fp32 out
// MODE 5 (ZX): A = xb via gload16; plain bf16 store -> zxb
// Modes 3/4/5: T4 counted-vmcnt 2-phase loop (R14).
// Bt is [N][K] bf16 pre-transposed. grid = mtc*8*NT (1-D).
// ---------------------------------------------------------------------------
template<int MODE, int K, int N, int NT, bool EAB>
__global__ __launch_bounds__(256, (MODE == 1) ? 4 : 1)
void gemm_k(const unsigned short* __restrict__ A,        // mode4: H3
            const unsigned short* __restrict__ xb,       // bf16 x
            const unsigned short* __restrict__ eas,      // bf16 sorted edge_attr
            const float* __restrict__ eaf,               // fp32 edge_attr
            const float* __restrict__ aggH_in,           // mode2 A source
            const float* __restrict__ cnt,
            const unsigned short* __restrict__ agg2b_in, // mode3 A source k>=256
            const unsigned short* __restrict__ zxb,      // mode1 LDS-staged gather
            const int* __restrict__ perm,                // sorted->orig edge
            const int* __restrict__ ssrc,                // sorted src node
            const int* __restrict__ sdst,                // sorted dest node
            const unsigned short* __restrict__ Bt,
            const float* __restrict__ bias,
            float* __restrict__ outf,                    // mode1: aggH ; mode4: out
            unsigned short* __restrict__ outb,           // mode2/3/5 bf16 out
            int M, int base, int mt, int mtc)
{
  // XCD-chunked swizzle: NT n-tiles of one tile_m run consecutively on one XCD.
  const int bid = blockIdx.x;
  const int xcd = bid & 7;
  const int sl  = bid >> 3;
  const int tile_n = sl % NT;
  const int tile_m = xcd * mtc + sl / NT;
  if (tile_m >= mt) return;
  const int mbase = tile_m * 128;

  // smem layout:
  //  MODE 1: [0,8192) Al | [8192,16384) Bl | CL [128][66] bf16 in [0,16896)
  //          [16896,33280) ZLh [128][64] bf16 (half-tile, both rounds)
  //          [33280,34816) runs_s/e/d | [34816,34832) wmask
  //  MODE 2: single buffer 16 KB
  //  else  : double buffer  [0,16384) buf0 (Al|Bl) | [16384,32768) buf1
  constexpr int SMEM = (MODE == 1) ? 34832 : ((MODE == 2) ? 16384 : 32768);
  __shared__ __align__(16) char smem[SMEM];

  const int t = threadIdx.x;
  const int w = t >> 6, l = t & 63;
  const int wr = w >> 1, wc = w & 1;
  const int lr = l & 15, lk = l >> 4;

  fx4 zero = {0.f, 0.f, 0.f, 0.f};
  fx4 acc[4][4];
#pragma unroll
  for (int i = 0; i < 4; i++)
#pragma unroll
    for (int j = 0; j < 4; j++) acc[i][j] = zero;

  // Stage one 128x32 A-tile + 128x32 B-tile into buffer b.
  auto STAGE = [&](int ks, int b) {
    const int k0 = ks * 32;
    char* Ab = (char*)smem + b * 16384;
    char* Bb = Ab + 8192;
#pragma unroll
    for (int it = 0; it < 2; ++it) {
      const int c = t + it * 256;          // 16B chunk id 0..511
      const int row = c >> 2, u = c & 3;
      gload16(Bt + (size_t)(tile_n * 128 + row) * K + (k0 + u * 8),
              Bb + c * 16);
      int rl = mbase + row; if (rl >= M) rl = M - 1;
      if constexpr (MODE == 1) {
        if constexpr (EAB) {
          gload16(eas + (size_t)rl * 256 + (k0 + u * 8), Ab + c * 16);
        } else {
          const int e = perm[rl];
          const float* s = eaf + (size_t)e * 256 + (k0 + u * 8);
          fx4 f0 = *(const fx4*)s, f1 = *(const fx4*)(s + 4);
          u16x8 v;
          v[0]=f2b(f0[0]); v[1]=f2b(f0[1]); v[2]=f2b(f0[2]); v[3]=f2b(f0[3]);
          v[4]=f2b(f1[0]); v[5]=f2b(f1[1]); v[6]=f2b(f1[2]); v[7]=f2b(f1[3]);
          *(u16x8*)(Ab + c * 16) = v;
        }
      } else if constexpr (MODE == 2) {
        // normalize moved to epilogue: stage raw bf16(aggH)
        const float* s = aggH_in + (size_t)rl * 1024 + (k0 + u * 8);
        fx4 f0 = *(const fx4*)s, f1 = *(const fx4*)(s + 4);
        u16x8 v;
        v[0]=f2b(f0[0]); v[1]=f2b(f0[1]); v[2]=f2b(f0[2]); v[3]=f2b(f0[3]);
        v[4]=f2b(f1[0]); v[5]=f2b(f1[1]); v[6]=f2b(f1[2]); v[7]=f2b(f1[3]);
        *(u16x8*)(Ab + c * 16) = v;
      } else if constexpr (MODE == 3) {
        const int node = base + rl;
        if (k0 < 256)
          gload16(xb + (size_t)node * 256 + (k0 + u * 8), Ab + c * 16);
        else
          gload16(agg2b_in + (size_t)node * 512 + (k0 - 256) + u * 8,
                  Ab + c * 16);
      } else if constexpr (MODE == 5) {
        gload16(xb + (size_t)rl * 256 + (k0 + u * 8), Ab + c * 16);
      } else {
        gload16(A + (size_t)rl * K + (k0 + u * 8), Ab + c * 16);
      }
    }
  };

  auto COMPUTE = [&](int b) {
    const unsigned short* Al = (const unsigned short*)((char*)smem + b * 16384);
    const unsigned short* Bl = Al + 4096;
    bf16x8 af[4], bfr[4];
    const int mb0 = wr * 64, nb0 = wc * 64;
#pragma unroll
    for (int i = 0; i < 4; i++)
      af[i] = *(const bf16x8*)(Al + (mb0 + i * 16 + lr) * 32 + lk * 8);
#pragma unroll
    for (int j = 0; j < 4; j++)
      bfr[j] = *(const bf16x8*)(Bl + (nb0 + j * 16 + lr) * 32 + lk * 8);
#pragma unroll
    for (int i = 0; i < 4; i++)
#pragma unroll
      for (int j = 0; j < 4; j++)
        acc[i][j] = __builtin_amdgcn_mfma_f32_16x16x32_bf16(af[i], bfr[j],
                                                            acc[i][j], 0, 0, 0);
  };

  // ZL half-tile gather [R15]: 1024 16B chunks cover 128 rows x 64 cols.
  // half h covers global cols tile_n*128 + (u&4 ? 64:0) + h*32 + (u&3)*8.
  auto ZSTAGE = [&](int h) {
#pragma unroll
    for (int q2 = 0; q2 < 4; ++q2) {
      const int c = q2 * 256 + t;          // 0..1023
      const int zrow = c >> 3, u = c & 7;
      int gr = mbase + zrow; if (gr >= M) gr = M - 1;
      const int coff = tile_n * 128 + ((u & 4) ? 64 : 0) + h * 32 + (u & 3) * 8;
      gload16(zxb + (size_t)ssrc[gr] * 1024 + coff, (char*)smem + 16896 + c * 16);
    }
  };

  const int NK = K / 32;
  if constexpr (MODE == 1) {
    ZSTAGE(0);   // half-0: drained by the first K-loop barrier
    for (int ks = 0; ks < NK; ++ks) {
      STAGE(ks, 0);
      __syncthreads();
      COMPUTE(0);
      __syncthreads();
    }
  } else if constexpr (MODE == 2) {
    for (int ks = 0; ks < NK; ++ks) {
      STAGE(ks, 0);
      __syncthreads();
      COMPUTE(0);
      __syncthreads();
    }
  } else {
    // T4 counted-vmcnt 2-phase loop [R14]
    STAGE(0, 0);
    for (int ks = 0; ks < NK; ++ks) {
      const int cur = ks & 1;
      if (ks + 1 < NK) {
        STAGE(ks + 1, cur ^ 1);
        asm volatile("s_waitcnt vmcnt(4)" ::: "memory");
      } else {
        asm volatile("s_waitcnt vmcnt(0)" ::: "memory");
      }
      __builtin_amdgcn_s_barrier();
      COMPUTE(cur);
      __builtin_amdgcn_s_barrier();
    }
  }

  // Epilogue. C/D layout: col = lane&15, row = (lane>>4)*4 + reg  [m89]
  if constexpr (MODE == 1) {
    // ---- ballot-compacted run merge; 2 rounds of 64 cols, bf16 CL [R15] ----
    int rows = M - mbase; if (rows > 128) rows = 128;
    unsigned short* CL = (unsigned short*)smem;       // [128][66] u16, 16896 B
    unsigned short* ZLh = (unsigned short*)(smem + 16896); // [128][64] u16
    int* runs_s = (int*)(smem + 33280);               // 128
    int* runs_e = (int*)(smem + 33792);               // 128
    int* runs_d = (int*)(smem + 34304);               // 128
    unsigned long long* wmask = (unsigned long long*)(smem + 34816); // 2
    int flag = 0;
    if (t < 128)
      flag = (t < rows) && ((t == 0) || (sdst[mbase + t] != sdst[mbase + t - 1]));
    unsigned long long bm = __ballot(flag);
    if (l == 0 && w < 2) wmask[w] = bm;
    __syncthreads();
    const unsigned long long m0 = wmask[0], m1 = wmask[1];
    const int nruns = __builtin_popcountll(m0) + __builtin_popcountll(m1);
    if (flag) {
      int rank, rend;
      if (t < 64) {
        rank = __builtin_popcountll(m0 & ((t == 0) ? 0ull : ((1ull << t) - 1)));
        unsigned long long above = (t == 63) ? 0ull : (m0 & (~0ull << (t + 1)));
        if (above) rend = __builtin_ctzll(above);
        else if (m1) rend = 64 + __builtin_ctzll(m1);
        else rend = rows;
      } else {
        const int tt = t - 64;
        rank = __builtin_popcountll(m0) +
               __builtin_popcountll(m1 & ((tt == 0) ? 0ull : ((1ull << tt) - 1)));
        unsigned long long above = (tt == 63) ? 0ull : (m1 & (~0ull << (tt + 1)));
        rend = above ? 64 + __builtin_ctzll(above) : rows;
      }
      runs_s[rank] = t; runs_e[rank] = rend; runs_d[rank] = sdst[mbase + t];
    }
    const int lc = wc * 16 + lr;            // local col 0..31 within a j-group
    const int nn_base = tile_n * 128 + wc * 64 + lr;
    for (int jj = 0; jj < 2; ++jj) {
#pragma unroll
      for (int jp = 0; jp < 2; ++jp) {
        const int j = jj * 2 + jp;
        const float bj = bias[nn_base + j * 16];
        const int q = wc * 32 + jp * 16 + lr;      // col within ZLh
#pragma unroll
        for (int i = 0; i < 4; i++)
#pragma unroll
          for (int r = 0; r < 4; r++) {
            const int lrow = wr * 64 + i * 16 + lk * 4 + r;
            float v = acc[i][j][r] + bj + b2f(ZLh[lrow * 64 + q]);
            v = v >= 0.f ? v : 0.01f * v;
            CL[lrow * 66 + jp * 32 + lc] = f2b(v);
          }
      }
      __syncthreads();                 // all ZLh(half jj) reads done
      if (jj == 0) ZSTAGE(1);          // half-1 gather hides under merge below
      for (int task = t; task < nruns * 64; task += 256) {
        const int ri = task >> 6, c = task & 63;
        const int rs = runs_s[ri], re = runs_e[ri];
        float s = 0.f;
        for (int r = rs; r < re; ++r) s += b2f(CL[r * 66 + c]);
        const int jp = c >> 5, w16 = (c >> 4) & 1, clr = c & 15;
        const int n = tile_n * 128 + w16 * 64 + (jj * 2 + jp) * 16 + clr;
        float* addr = outf + (size_t)runs_d[ri] * 1024 + n;
        const bool open = (rs == 0 && mbase > 0) || (re == rows && mbase + rows < M);
        if (open) atomicAdd(addr, s); else *addr = s;
      }
      __syncthreads();                 // drains half-1 gather before round 1
    }
  } else {
#pragma unroll
    for (int j = 0; j < 4; j++) {
      const int n = tile_n * 128 + wc * 64 + j * 16 + lr;
      float bj = 0.f;
      if constexpr (MODE == 2 || MODE == 3 || MODE == 4) bj = bias[n];
#pragma unroll
      for (int i = 0; i < 4; i++) {
        const int m0 = mbase + wr * 64 + i * 16 + lk * 4;
#pragma unroll
        for (int r = 0; r < 4; r++) {
          const int m = m0 + r;
          if (m < M) {
            float v = acc[i][j][r];
            if constexpr (MODE == 2) {
              const float ct = cnt[m];
              v = v / fmaxf(ct, 1.f) + (ct > 0.f ? bj : 0.f);
              outb[(size_t)m * N + n] = f2b(v);
            } else if constexpr (MODE == 3) {
              v += bj;
              v = v >= 0.f ? v : 0.01f * v;
              outb[(size_t)m * N + n] = f2b(v);
            } else if constexpr (MODE == 5) {
              outb[(size_t)m * N + n] = f2b(v);
            } else {
              outf[(size_t)(base + m) * N + n] = v + bj;
            }
          }
        }
      }
    }
  }
}

// ---------------------------------------------------------------------------
// Helper kernels
// ---------------------------------------------------------------------------
// fused: edge_index repack (int64->int32 autodetect) + dest-count atomics
__global__ void fixcnt_k(const int* __restrict__ src, int* __restrict__ dst,
                         float* __restrict__ cnt, int E) {
  int i = blockIdx.x * blockDim.x + threadIdx.x;
  if (i >= 2 * E) return;
  bool is64 = true;
#pragma unroll
  for (int p = 0; p < 16; ++p) is64 = is64 && (src[2 * p + 1] == 0);
  const int v = is64 ? src[2 * i] : src[i];
  dst[i] = v;
  if (i >= E) atomicAdd(cnt + v, 1.f);   // dest half -> in-degree counts
}

__global__ void cvt_f2b_k(const float* __restrict__ x, unsigned short* __restrict__ o,
                          long n4) {
  long i = (long)blockIdx.x * blockDim.x + threadIdx.x;
  if (i < n4) {
    fx4 f = *(const fx4*)(x + i * 4);
    u16x4 v; v[0]=f2b(f[0]); v[1]=f2b(f[1]); v[2]=f2b(f[2]); v[3]=f2b(f[3]);
    *(u16x4*)(o + i * 4) = v;
  }
}

// eas[s][0:256] = bf16(ea[perm[s]][0:256])  (gather rows into sorted order)
__global__ void cvt_eas_k(const float* __restrict__ ea, const int* __restrict__ perm,
                          unsigned short* __restrict__ eas, int E) {
  long i = (long)blockIdx.x * blockDim.x + threadIdx.x;
  if (i >= (long)E * 64) return;
  const int s = (int)(i >> 6), q = (int)(i & 63);
  const float* src = ea + (size_t)perm[s] * 256 + q * 4;
  fx4 f = *(const fx4*)src;
  u16x4 v; v[0]=f2b(f[0]); v[1]=f2b(f[1]); v[2]=f2b(f[2]); v[3]=f2b(f[3]);
  *(u16x4*)(eas + (size_t)s * 256 + q * 4) = v;
}

// W[K][N] fp32 -> Wt[N][K] bf16
__global__ void cvt_w_k(const float* __restrict__ W, unsigned short* __restrict__ Wt,
                        int K, int N) {
  long i = (long)blockIdx.x * blockDim.x + threadIdx.x;
  if (i < (long)K * N) {
    int k = (int)(i / N), n = (int)(i % N);
    Wt[(size_t)n * K + k] = f2b(W[i]);
  }
}

// zero rows of aggH that will receive atomicAdd: first/last run dest per tile
__global__ void zb_k(const int* __restrict__ sdst, float* __restrict__ aggH,
                     int M, int mt) {
  const int b = blockIdx.x;            // 0..2*mt-1
  int row = (b >> 1) * 128 + ((b & 1) ? 127 : 0);
  if (row >= M) row = M - 1;
  const int dest = sdst[row];
  fx4 z = {0.f, 0.f, 0.f, 0.f};
  *(fx4*)(aggH + (size_t)dest * 1024 + threadIdx.x * 4) = z;
}

// zero rows of aggH for nodes with no incoming edges (grid-stride; ~2 rows)
__global__ void zc_k(const float* __restrict__ cnt, float* __restrict__ aggH,
                     int Nn) {
  fx4 z = {0.f, 0.f, 0.f, 0.f};
  for (int nidx = blockIdx.x * blockDim.x + threadIdx.x; nidx < Nn;
       nidx += gridDim.x * blockDim.x) {
    if (cnt[nidx] != 0.f) continue;
    float* row = aggH + (size_t)nidx * 1024;
    for (int q = 0; q < 256; ++q) *(fx4*)(row + q * 4) = z;
  }
}

// Single-block exclusive scan of (int)cnt -> pos  (Hillis-Steele per chunk)
__global__ __launch_bounds__(1024)
void scan_k(const float* __restrict__ cnt, int* __restrict__ pos, int Nn) {
  __shared__ int sdata[1024];
  __shared__ int carry;
  if (threadIdx.x == 0) carry = 0;
  __syncthreads();
  for (int bb = 0; bb < Nn; bb += 1024) {
    const int i = bb + threadIdx.x;
    const int v = (i < Nn) ? (int)cnt[i] : 0;
    sdata[threadIdx.x] = v;
    __syncthreads();
    for (int off = 1; off < 1024; off <<= 1) {
      int tv = (threadIdx.x >= off) ? sdata[threadIdx.x - off] : 0;
      __syncthreads();
      sdata[threadIdx.x] += tv;
      __syncthreads();
    }
    const int excl = sdata[threadIdx.x] - v + carry;
    if (i < Nn) pos[i] = excl;
    __syncthreads();
    if (threadIdx.x == 1023) carry += sdata[1023];
    __syncthreads();
  }
}

// counting-sort scatter: perm (sorted->orig), ssrc, sdst
__global__ void perm_k(const int* __restrict__ idx, int E, int* __restrict__ pos,
                       int* __restrict__ perm, int* __restrict__ ssrc,
                       int* __restrict__ sdst) {
  int e = blockIdx.x * blockDim.x + threadIdx.x;
  if (e >= E) return;
  const int d = idx[E + e];
  const int s = atomicAdd(pos + d, 1);
  perm[s] = e;
  ssrc[s] = idx[e];
  sdst[s] = d;
}

// ---------------------------------------------------------------------------
extern "C" void kernel_launch(void* const* d_in, const int* in_sizes, int n_in,
                              void* d_out, int out_size, void* d_ws, size_t ws_size,
                              hipStream_t stream)
{
  const float* x  = (const float*)d_in[0];
  const int* eraw = (const int*)d_in[1];
  const float* ea = (const float*)d_in[2];
  const float* W1 = (const float*)d_in[5];
  const float* b1 = (const float*)d_in[6];
  const float* W2 = (const float*)d_in[7];
  const float* b2 = (const float*)d_in[8];
  const float* W3 = (const float*)d_in[9];
  const float* b3 = (const float*)d_in[10];
  const float* W4 = (const float*)d_in[11];
  const float* b4 = (const float*)d_in[12];
  float* out = (float*)d_out;

  const int Nn = in_sizes[0] / 256;   // 50000
  const int E  = in_sizes[1] / 2;     // 500000

  // ---- workspace carve (256B-aligned bump allocator) ----
  char* p = (char*)d_ws;
  auto take = [&](size_t bytes) -> char* {
    char* r = p; p += (bytes + 255) & ~(size_t)255; return r;
  };
  unsigned short* W1xt = (unsigned short*)take((size_t)1024 * 256 * 2);
  unsigned short* W1et = (unsigned short*)take((size_t)1024 * 256 * 2);
  unsigned short* W2t  = (unsigned short*)take((size_t)1024 * 512 * 2);
  unsigned short* W3t  = (unsigned short*)take((size_t)768 * 1536 * 2);
  unsigned short* W4t  = (unsigned short*)take((size_t)1536 * 256 * 2);
  int* idx  = (int*)take((size_t)2 * E * 4);
  float* cnt  = (float*)take((size_t)Nn * 4);
  float* aggH = (float*)take((size_t)Nn * 1024 * 4);      // layer-1 scatter-sum
  unsigned short* agg2b = (unsigned short*)take((size_t)Nn * 512 * 2);
  unsigned short* xb    = (unsigned short*)take((size_t)Nn * 256 * 2);
  unsigned short* zxb   = (unsigned short*)take((size_t)Nn * 1024 * 2);
  int* pos  = (int*)take((size_t)Nn * 4);
  int* perm = (int*)take((size_t)E * 4);
  int* ssrc = (int*)take((size_t)E * 4);
  int* sdst = (int*)take((size_t)E * 4);

  long avail = (long)ws_size - (long)(p - (char*)d_ws);

  unsigned short* eas = nullptr;              // sorted bf16 edge_attr (optional)
  const long eas_bytes = (((long)E * 256 * 2) + 255) & ~255L;
  if (avail >= eas_bytes + 128 * 3072 + 1024) {
    eas = (unsigned short*)take((size_t)E * 256 * 2);
    avail -= eas_bytes;
  }
  long bandN = avail / 3072;  bandN &= ~127L;
  if (bandN > 50048) bandN = 50048;
  if (bandN < 128)   bandN = 128;
  unsigned short* H3 = (unsigned short*)take((size_t)bandN * 3072);

  const int mtE = (E + 127) / 128;

  hipMemsetAsync(cnt, 0, (size_t)Nn * 4, stream);
  fixcnt_k<<<(2 * E + 255) / 256, 256, 0, stream>>>(eraw, idx, cnt, E);
  scan_k<<<1, 1024, 0, stream>>>(cnt, pos, Nn);
  perm_k<<<(E + 255) / 256, 256, 0, stream>>>(idx, E, pos, perm, ssrc, sdst);
  // targeted zeroing of atomicAdd-target rows (replaces 205 MB memset)
  zb_k<<<mtE * 2, 256, 0, stream>>>(sdst, aggH, E, mtE);
  zc_k<<<104, 256, 0, stream>>>(cnt, aggH, Nn);
  cvt_f2b_k<<<(Nn * 64 + 255) / 256, 256, 0, stream>>>(x, xb, (long)Nn * 64);
  if (eas)
    cvt_eas_k<<<(int)(((long)E * 64 + 255) / 256), 256, 0, stream>>>(ea, perm,
                                                                     eas, E);
  cvt_w_k<<<(256 * 1024 + 255) / 256, 256, 0, stream>>>(W1, W1xt, 256, 1024);
  cvt_w_k<<<(256 * 1024 + 255) / 256, 256, 0, stream>>>(W1 + 256 * 1024, W1et,
                                                        256, 1024);
  cvt_w_k<<<(1024 * 512 + 255) / 256, 256, 0, stream>>>(W2, W2t, 1024, 512);
  cvt_w_k<<<(768 * 1536 + 255) / 256, 256, 0, stream>>>(W3, W3t, 768, 1536);
  cvt_w_k<<<(1536 * 256 + 255) / 256, 256, 0, stream>>>(W4, W4t, 1536, 256);

  // ZX: zxb = bf16(x @ W1x)   [x-half of layer 1, deduped to nodes]
  {
    const int mt = (Nn + 127) / 128, mtc = (mt + 7) / 8;
    gemm_k<5, 256, 1024, 8, false><<<mtc * 8 * 8, 256, 0, stream>>>(
        nullptr, xb, nullptr, nullptr, nullptr, nullptr, nullptr, nullptr,
        nullptr, nullptr, nullptr, W1xt, nullptr, nullptr, zxb, Nn, 0, mt, mtc);
  }

  // G1': edge layer-1 (ea half, K=256) + split-ZL zxb staging + run-merge
  {
    const int mt = mtE, mtc = (mt + 7) / 8;
    const int grid = mtc * 8 * 8;
    if (eas)
      gemm_k<1, 256, 1024, 8, true><<<grid, 256, 0, stream>>>(
          nullptr, nullptr, eas, ea, nullptr, nullptr, nullptr, zxb, perm,
          ssrc, sdst, W1et, b1, aggH, nullptr, E, 0, mt, mtc);
    else
      gemm_k<1, 256, 1024, 8, false><<<grid, 256, 0, stream>>>(
          nullptr, nullptr, nullptr, ea, nullptr, nullptr, nullptr, zxb, perm,
          ssrc, sdst, W1et, b1, aggH, nullptr, E, 0, mt, mtc);
  }

  // A2: agg2 = (aggH @ W2)/max(cnt,1) + (cnt>0)*b2   [normalize in epilogue]
  {
    const int mt = (Nn + 127) / 128, mtc = (mt + 7) / 8;
    gemm_k<2, 1024, 512, 4, false><<<mtc * 8 * 4, 256, 0, stream>>>(
        nullptr, nullptr, nullptr, nullptr, aggH, cnt, nullptr, nullptr,
        nullptr, nullptr, nullptr, W2t, b2, nullptr, agg2b, Nn, 0, mt, mtc);
  }

  // node MLP, banded over nodes
  for (long base = 0; base < Nn; base += bandN) {
    long rem = Nn - base;
    int mb = (int)(rem < bandN ? rem : bandN);
    int mt = (mb + 127) / 128, mtc = (mt + 7) / 8;
    gemm_k<3, 768, 1536, 12, false><<<mtc * 8 * 12, 256, 0, stream>>>(
        nullptr, xb, nullptr, nullptr, nullptr, nullptr, agg2b, nullptr,
        nullptr, nullptr, nullptr, W3t, b3, nullptr, H3, mb, (int)base, mt, mtc);
    gemm_k<4, 1536, 256, 2, false><<<mtc * 8 * 2, 256, 0, stream>>>(
        H3, nullptr, nullptr, nullptr, nullptr, nullptr, nullptr, nullptr,
        nullptr, nullptr, nullptr, W4t, b4, out, nullptr, mb, (int)base, mt, mtc);
  }
}

// Round 18
// 1543.453 us; speedup vs baseline: 1.0263x; 1.0179x over previous
//
#include <hip/hip_runtime.h>

typedef __bf16 bf16x8 __attribute__((ext_vector_type(8)));
typedef float fx4 __attribute__((ext_vector_type(4)));
typedef unsigned short u16x8 __attribute__((ext_vector_type(8)));
typedef unsigned short u16x4 __attribute__((ext_vector_type(4)));

__device__ __forceinline__ unsigned short f2b(float f) {
  unsigned u = __float_as_uint(f);
  u = (u + 0x7fffu + ((u >> 16) & 1u)) >> 16;
  return (unsigned short)u;
}
__device__ __forceinline__ float b2f(unsigned short s) {
  return __uint_as_float((unsigned)s << 16);
}

__device__ __forceinline__ void gload16(const void* g, void* l) {
  __builtin_amdgcn_global_load_lds(
      (const __attribute__((address_space(1))) unsigned int*)g,
      (__attribute__((address_space(3))) unsigned int*)l, 16, 0, 0);
}

// ---------------------------------------------------------------------------
// 128x128-tile bf16 MFMA GEMM, XCD-chunked block swizzle.  [R15/R17 structure]
// MODE 1 (G1'): rows = dest-sorted edges, K=256. A = eas[s]. zxb tile split
//   into two 16 KB halves: half-0 staged in prologue, half-1 issued after
//   round-0's CL sync. LDS 34.8 KB, __launch_bounds__(256,4). Epilogue:
//   v = acc + b1[n] + ZLh, leaky -> bf16 CL [128][66]; 2-round ballot-
//   compacted run merge; interior runs plain-store into aggH[dest], boundary
//   runs atomicAdd (rows pre-zeroed by zb_k/zc_k).
// MODE 2 (A2): A = bf16(aggH[node]); normalize in epilogue: /max(cnt,1)
//   + (cnt>0)*b2 -> agg2b bf16.  Legacy __syncthreads loop, bounds (256,1).
// MODE 3 (G3): A = concat [xb|agg2b] via gload16; +b3, leaky -> H3 bf16
// MODE 4 (G4): A = H3 via gload16; +b4 -> fp32 out
// MODE 5 (ZX): A = xb via gload16; plain bf16 store -> zxb
// Modes 3/4/5: T4 counted-vmcnt 2-phase loop (R14) + __launch_bounds__(256,4)
//   (R15-proven occupancy unlock: VGPR cap 64, 4 blocks/CU).
// Bt is [N][K] bf16 pre-transposed. grid = mtc*8*NT (1-D).
// ---------------------------------------------------------------------------
template<int MODE, int K, int N, int NT, bool EAB>
__global__ __launch_bounds__(256, (MODE == 2) ? 1 : 4)
void gemm_k(const unsigned short* __restrict__ A,        // mode4: H3
            const unsigned short* __restrict__ xb,       // bf16 x
            const unsigned short* __restrict__ eas,      // bf16 sorted edge_attr
            const float* __restrict__ eaf,               // fp32 edge_attr
            const float* __restrict__ aggH_in,           // mode2 A source
            const float* __restrict__ cnt,
            const unsigned short* __restrict__ agg2b_in, // mode3 A source k>=256
            const unsigned short* __restrict__ zxb,      // mode1 LDS-staged gather
            const int* __restrict__ perm,                // sorted->orig edge
            const int* __restrict__ ssrc,                // sorted src node
            const int* __restrict__ sdst,                // sorted dest node
            const unsigned short* __restrict__ Bt,
            const float* __restrict__ bias,
            float* __restrict__ outf,                    // mode1: aggH ; mode4: out
            unsigned short* __restrict__ outb,           // mode2/3/5 bf16 out
            int M, int base, int mt, int mtc)
{
  // XCD-chunked swizzle: NT n-tiles of one tile_m run consecutively on one XCD.
  const int bid = blockIdx.x;
  const int xcd = bid & 7;
  const int sl  = bid >> 3;
  const int tile_n = sl % NT;
  const int tile_m = xcd * mtc + sl / NT;
  if (tile_m >= mt) return;
  const int mbase = tile_m * 128;

  // smem layout:
  //  MODE 1: [0,8192) Al | [8192,16384) Bl | CL [128][66] bf16 in [0,16896)
  //          [16896,33280) ZLh [128][64] bf16 (half-tile, both rounds)
  //          [33280,34816) runs_s/e/d | [34816,34832) wmask
  //  MODE 2: single buffer 16 KB
  //  else  : double buffer  [0,16384) buf0 (Al|Bl) | [16384,32768) buf1
  constexpr int SMEM = (MODE == 1) ? 34832 : ((MODE == 2) ? 16384 : 32768);
  __shared__ __align__(16) char smem[SMEM];

  const int t = threadIdx.x;
  const int w = t >> 6, l = t & 63;
  const int wr = w >> 1, wc = w & 1;
  const int lr = l & 15, lk = l >> 4;

  fx4 zero = {0.f, 0.f, 0.f, 0.f};
  fx4 acc[4][4];
#pragma unroll
  for (int i = 0; i < 4; i++)
#pragma unroll
    for (int j = 0; j < 4; j++) acc[i][j] = zero;

  // Stage one 128x32 A-tile + 128x32 B-tile into buffer b.
  auto STAGE = [&](int ks, int b) {
    const int k0 = ks * 32;
    char* Ab = (char*)smem + b * 16384;
    char* Bb = Ab + 8192;
#pragma unroll
    for (int it = 0; it < 2; ++it) {
      const int c = t + it * 256;          // 16B chunk id 0..511
      const int row = c >> 2, u = c & 3;
      gload16(Bt + (size_t)(tile_n * 128 + row) * K + (k0 + u * 8),
              Bb + c * 16);
      int rl = mbase + row; if (rl >= M) rl = M - 1;
      if constexpr (MODE == 1) {
        if constexpr (EAB) {
          gload16(eas + (size_t)rl * 256 + (k0 + u * 8), Ab + c * 16);
        } else {
          const int e = perm[rl];
          const float* s = eaf + (size_t)e * 256 + (k0 + u * 8);
          fx4 f0 = *(const fx4*)s, f1 = *(const fx4*)(s + 4);
          u16x8 v;
          v[0]=f2b(f0[0]); v[1]=f2b(f0[1]); v[2]=f2b(f0[2]); v[3]=f2b(f0[3]);
          v[4]=f2b(f1[0]); v[5]=f2b(f1[1]); v[6]=f2b(f1[2]); v[7]=f2b(f1[3]);
          *(u16x8*)(Ab + c * 16) = v;
        }
      } else if constexpr (MODE == 2) {
        // normalize moved to epilogue: stage raw bf16(aggH)
        const float* s = aggH_in + (size_t)rl * 1024 + (k0 + u * 8);
        fx4 f0 = *(const fx4*)s, f1 = *(const fx4*)(s + 4);
        u16x8 v;
        v[0]=f2b(f0[0]); v[1]=f2b(f0[1]); v[2]=f2b(f0[2]); v[3]=f2b(f0[3]);
        v[4]=f2b(f1[0]); v[5]=f2b(f1[1]); v[6]=f2b(f1[2]); v[7]=f2b(f1[3]);
        *(u16x8*)(Ab + c * 16) = v;
      } else if constexpr (MODE == 3) {
        const int node = base + rl;
        if (k0 < 256)
          gload16(xb + (size_t)node * 256 + (k0 + u * 8), Ab + c * 16);
        else
          gload16(agg2b_in + (size_t)node * 512 + (k0 - 256) + u * 8,
                  Ab + c * 16);
      } else if constexpr (MODE == 5) {
        gload16(xb + (size_t)rl * 256 + (k0 + u * 8), Ab + c * 16);
      } else {
        gload16(A + (size_t)rl * K + (k0 + u * 8), Ab + c * 16);
      }
    }
  };

  auto COMPUTE = [&](int b) {
    const unsigned short* Al = (const unsigned short*)((char*)smem + b * 16384);
    const unsigned short* Bl = Al + 4096;
    bf16x8 af[4], bfr[4];
    const int mb0 = wr * 64, nb0 = wc * 64;
#pragma unroll
    for (int i = 0; i < 4; i++)
      af[i] = *(const bf16x8*)(Al + (mb0 + i * 16 + lr) * 32 + lk * 8);
#pragma unroll
    for (int j = 0; j < 4; j++)
      bfr[j] = *(const bf16x8*)(Bl + (nb0 + j * 16 + lr) * 32 + lk * 8);
#pragma unroll
    for (int i = 0; i < 4; i++)
#pragma unroll
      for (int j = 0; j < 4; j++)
        acc[i][j] = __builtin_amdgcn_mfma_f32_16x16x32_bf16(af[i], bfr[j],
                                                            acc[i][j], 0, 0, 0);
  };

  // ZL half-tile gather [R15]: 1024 16B chunks cover 128 rows x 64 cols.
  // half h covers global cols tile_n*128 + (u&4 ? 64:0) + h*32 + (u&3)*8.
  auto ZSTAGE = [&](int h) {
#pragma unroll
    for (int q2 = 0; q2 < 4; ++q2) {
      const int c = q2 * 256 + t;          // 0..1023
      const int zrow = c >> 3, u = c & 7;
      int gr = mbase + zrow; if (gr >= M) gr = M - 1;
      const int coff = tile_n * 128 + ((u & 4) ? 64 : 0) + h * 32 + (u & 3) * 8;
      gload16(zxb + (size_t)ssrc[gr] * 1024 + coff, (char*)smem + 16896 + c * 16);
    }
  };

  const int NK = K / 32;
  if constexpr (MODE == 1) {
    ZSTAGE(0);   // half-0: drained by the first K-loop barrier
    for (int ks = 0; ks < NK; ++ks) {
      STAGE(ks, 0);
      __syncthreads();
      COMPUTE(0);
      __syncthreads();
    }
  } else if constexpr (MODE == 2) {
    for (int ks = 0; ks < NK; ++ks) {
      STAGE(ks, 0);
      __syncthreads();
      COMPUTE(0);
      __syncthreads();
    }
  } else {
    // T4 counted-vmcnt 2-phase loop [R14]
    STAGE(0, 0);
    for (int ks = 0; ks < NK; ++ks) {
      const int cur = ks & 1;
      if (ks + 1 < NK) {
        STAGE(ks + 1, cur ^ 1);
        asm volatile("s_waitcnt vmcnt(4)" ::: "memory");
      } else {
        asm volatile("s_waitcnt vmcnt(0)" ::: "memory");
      }
      __builtin_amdgcn_s_barrier();
      COMPUTE(cur);
      __builtin_amdgcn_s_barrier();
    }
  }

  // Epilogue. C/D layout: col = lane&15, row = (lane>>4)*4 + reg  [m89]
  if constexpr (MODE == 1) {
    // ---- ballot-compacted run merge; 2 rounds of 64 cols, bf16 CL [R15] ----
    int rows = M - mbase; if (rows > 128) rows = 128;
    unsigned short* CL = (unsigned short*)smem;       // [128][66] u16, 16896 B
    unsigned short* ZLh = (unsigned short*)(smem + 16896); // [128][64] u16
    int* runs_s = (int*)(smem + 33280);               // 128
    int* runs_e = (int*)(smem + 33792);               // 128
    int* runs_d = (int*)(smem + 34304);               // 128
    unsigned long long* wmask = (unsigned long long*)(smem + 34816); // 2
    int flag = 0;
    if (t < 128)
      flag = (t < rows) && ((t == 0) || (sdst[mbase + t] != sdst[mbase + t - 1]));
    unsigned long long bm = __ballot(flag);
    if (l == 0 && w < 2) wmask[w] = bm;
    __syncthreads();
    const unsigned long long m0 = wmask[0], m1 = wmask[1];
    const int nruns = __builtin_popcountll(m0) + __builtin_popcountll(m1);
    if (flag) {
      int rank, rend;
      if (t < 64) {
        rank = __builtin_popcountll(m0 & ((t == 0) ? 0ull : ((1ull << t) - 1)));
        unsigned long long above = (t == 63) ? 0ull : (m0 & (~0ull << (t + 1)));
        if (above) rend = __builtin_ctzll(above);
        else if (m1) rend = 64 + __builtin_ctzll(m1);
        else rend = rows;
      } else {
        const int tt = t - 64;
        rank = __builtin_popcountll(m0) +
               __builtin_popcountll(m1 & ((tt == 0) ? 0ull : ((1ull << tt) - 1)));
        unsigned long long above = (tt == 63) ? 0ull : (m1 & (~0ull << (tt + 1)));
        rend = above ? 64 + __builtin_ctzll(above) : rows;
      }
      runs_s[rank] = t; runs_e[rank] = rend; runs_d[rank] = sdst[mbase + t];
    }
    const int lc = wc * 16 + lr;            // local col 0..31 within a j-group
    const int nn_base = tile_n * 128 + wc * 64 + lr;
    for (int jj = 0; jj < 2; ++jj) {
#pragma unroll
      for (int jp = 0; jp < 2; ++jp) {
        const int j = jj * 2 + jp;
        const float bj = bias[nn_base + j * 16];
        const int q = wc * 32 + jp * 16 + lr;      // col within ZLh
#pragma unroll
        for (int i = 0; i < 4; i++)
#pragma unroll
          for (int r = 0; r < 4; r++) {
            const int lrow = wr * 64 + i * 16 + lk * 4 + r;
            float v = acc[i][j][r] + bj + b2f(ZLh[lrow * 64 + q]);
            v = v >= 0.f ? v : 0.01f * v;
            CL[lrow * 66 + jp * 32 + lc] = f2b(v);
          }
      }
      __syncthreads();                 // all ZLh(half jj) reads done
      if (jj == 0) ZSTAGE(1);          // half-1 gather hides under merge below
      for (int task = t; task < nruns * 64; task += 256) {
        const int ri = task >> 6, c = task & 63;
        const int rs = runs_s[ri], re = runs_e[ri];
        float s = 0.f;
        for (int r = rs; r < re; ++r) s += b2f(CL[r * 66 + c]);
        const int jp = c >> 5, w16 = (c >> 4) & 1, clr = c & 15;
        const int n = tile_n * 128 + w16 * 64 + (jj * 2 + jp) * 16 + clr;
        float* addr = outf + (size_t)runs_d[ri] * 1024 + n;
        const bool open = (rs == 0 && mbase > 0) || (re == rows && mbase + rows < M);
        if (open) atomicAdd(addr, s); else *addr = s;
      }
      __syncthreads();                 // drains half-1 gather before round 1
    }
  } else {
#pragma unroll
    for (int j = 0; j < 4; j++) {
      const int n = tile_n * 128 + wc * 64 + j * 16 + lr;
      float bj = 0.f;
      if constexpr (MODE == 2 || MODE == 3 || MODE == 4) bj = bias[n];
#pragma unroll
      for (int i = 0; i < 4; i++) {
        const int m0 = mbase + wr * 64 + i * 16 + lk * 4;
#pragma unroll
        for (int r = 0; r < 4; r++) {
          const int m = m0 + r;
          if (m < M) {
            float v = acc[i][j][r];
            if constexpr (MODE == 2) {
              const float ct = cnt[m];
              v = v / fmaxf(ct, 1.f) + (ct > 0.f ? bj : 0.f);
              outb[(size_t)m * N + n] = f2b(v);
            } else if constexpr (MODE == 3) {
              v += bj;
              v = v >= 0.f ? v : 0.01f * v;
              outb[(size_t)m * N + n] = f2b(v);
            } else if constexpr (MODE == 5) {
              outb[(size_t)m * N + n] = f2b(v);
            } else {
              outf[(size_t)(base + m) * N + n] = v + bj;
            }
          }
        }
      }
    }
  }
}

// ---------------------------------------------------------------------------
// Helper kernels
// ---------------------------------------------------------------------------
// fused: edge_index repack (int64->int32 autodetect) + dest-count atomics
__global__ void fixcnt_k(const int* __restrict__ src, int* __restrict__ dst,
                         float* __restrict__ cnt, int E) {
  int i = blockIdx.x * blockDim.x + threadIdx.x;
  if (i >= 2 * E) return;
  bool is64 = true;
#pragma unroll
  for (int p = 0; p < 16; ++p) is64 = is64 && (src[2 * p + 1] == 0);
  const int v = is64 ? src[2 * i] : src[i];
  dst[i] = v;
  if (i >= E) atomicAdd(cnt + v, 1.f);   // dest half -> in-degree counts
}

__global__ void cvt_f2b_k(const float* __restrict__ x, unsigned short* __restrict__ o,
                          long n4) {
  long i = (long)blockIdx.x * blockDim.x + threadIdx.x;
  if (i < n4) {
    fx4 f = *(const fx4*)(x + i * 4);
    u16x4 v; v[0]=f2b(f[0]); v[1]=f2b(f[1]); v[2]=f2b(f[2]); v[3]=f2b(f[3]);
    *(u16x4*)(o + i * 4) = v;
  }
}

// eas[s][0:256] = bf16(ea[perm[s]][0:256])  (gather rows into sorted order)
__global__ void cvt_eas_k(const float* __restrict__ ea, const int* __restrict__ perm,
                          unsigned short* __restrict__ eas, int E) {
  long i = (long)blockIdx.x * blockDim.x + threadIdx.x;
  if (i >= (long)E * 64) return;
  const int s = (int)(i >> 6), q = (int)(i & 63);
  const float* src = ea + (size_t)perm[s] * 256 + q * 4;
  fx4 f = *(const fx4*)src;
  u16x4 v; v[0]=f2b(f[0]); v[1]=f2b(f[1]); v[2]=f2b(f[2]); v[3]=f2b(f[3]);
  *(u16x4*)(eas + (size_t)s * 256 + q * 4) = v;
}

// W[K][N] fp32 -> Wt[N][K] bf16
__global__ void cvt_w_k(const float* __restrict__ W, unsigned short* __restrict__ Wt,
                        int K, int N) {
  long i = (long)blockIdx.x * blockDim.x + threadIdx.x;
  if (i < (long)K * N) {
    int k = (int)(i / N), n = (int)(i % N);
    Wt[(size_t)n * K + k] = f2b(W[i]);
  }
}

// zero rows of aggH that will receive atomicAdd: first/last run dest per tile
__global__ void zb_k(const int* __restrict__ sdst, float* __restrict__ aggH,
                     int M, int mt) {
  const int b = blockIdx.x;            // 0..2*mt-1
  int row = (b >> 1) * 128 + ((b & 1) ? 127 : 0);
  if (row >= M) row = M - 1;
  const int dest = sdst[row];
  fx4 z = {0.f, 0.f, 0.f, 0.f};
  *(fx4*)(aggH + (size_t)dest * 1024 + threadIdx.x * 4) = z;
}

// zero rows of aggH for nodes with no incoming edges (grid-stride; ~2 rows)
__global__ void zc_k(const float* __restrict__ cnt, float* __restrict__ aggH,
                     int Nn) {
  fx4 z = {0.f, 0.f, 0.f, 0.f};
  for (int nidx = blockIdx.x * blockDim.x + threadIdx.x; nidx < Nn;
       nidx += gridDim.x * blockDim.x) {
    if (cnt[nidx] != 0.f) continue;
    float* row = aggH + (size_t)nidx * 1024;
    for (int q = 0; q < 256; ++q) *(fx4*)(row + q * 4) = z;
  }
}

// Single-block exclusive scan of (int)cnt -> pos  (Hillis-Steele per chunk)
__global__ __launch_bounds__(1024)
void scan_k(const float* __restrict__ cnt, int* __restrict__ pos, int Nn) {
  __shared__ int sdata[1024];
  __shared__ int carry;
  if (threadIdx.x == 0) carry = 0;
  __syncthreads();
  for (int bb = 0; bb < Nn; bb += 1024) {
    const int i = bb + threadIdx.x;
    const int v = (i < Nn) ? (int)cnt[i] : 0;
    sdata[threadIdx.x] = v;
    __syncthreads();
    for (int off = 1; off < 1024; off <<= 1) {
      int tv = (threadIdx.x >= off) ? sdata[threadIdx.x - off] : 0;
      __syncthreads();
      sdata[threadIdx.x] += tv;
      __syncthreads();
    }
    const int excl = sdata[threadIdx.x] - v + carry;
    if (i < Nn) pos[i] = excl;
    __syncthreads();
    if (threadIdx.x == 1023) carry += sdata[1023];
    __syncthreads();
  }
}

// counting-sort scatter: perm (sorted->orig), ssrc, sdst
__global__ void perm_k(const int* __restrict__ idx, int E, int* __restrict__ pos,
                       int* __restrict__ perm, int* __restrict__ ssrc,
                       int* __restrict__ sdst) {
  int e = blockIdx.x * blockDim.x + threadIdx.x;
  if (e >= E) return;
  const int d = idx[E + e];
  const int s = atomicAdd(pos + d, 1);
  perm[s] = e;
  ssrc[s] = idx[e];
  sdst[s] = d;
}

// ---------------------------------------------------------------------------
extern "C" void kernel_launch(void* const* d_in, const int* in_sizes, int n_in,
                              void* d_out, int out_size, void* d_ws, size_t ws_size,
                              hipStream_t stream)
{
  const float* x  = (const float*)d_in[0];
  const int* eraw = (const int*)d_in[1];
  const float* ea = (const float*)d_in[2];
  const float* W1 = (const float*)d_in[5];
  const float* b1 = (const float*)d_in[6];
  const float* W2 = (const float*)d_in[7];
  const float* b2 = (const float*)d_in[8];
  const float* W3 = (const float*)d_in[9];
  const float* b3 = (const float*)d_in[10];
  const float* W4 = (const float*)d_in[11];
  const float* b4 = (const float*)d_in[12];
  float* out = (float*)d_out;

  const int Nn = in_sizes[0] / 256;   // 50000
  const int E  = in_sizes[1] / 2;     // 500000

  // ---- workspace carve (256B-aligned bump allocator) ----
  char* p = (char*)d_ws;
  auto take = [&](size_t bytes) -> char* {
    char* r = p; p += (bytes + 255) & ~(size_t)255; return r;
  };
  unsigned short* W1xt = (unsigned short*)take((size_t)1024 * 256 * 2);
  unsigned short* W1et = (unsigned short*)take((size_t)1024 * 256 * 2);
  unsigned short* W2t  = (unsigned short*)take((size_t)1024 * 512 * 2);
  unsigned short* W3t  = (unsigned short*)take((size_t)768 * 1536 * 2);
  unsigned short* W4t  = (unsigned short*)take((size_t)1536 * 256 * 2);
  int* idx  = (int*)take((size_t)2 * E * 4);
  float* cnt  = (float*)take((size_t)Nn * 4);
  float* aggH = (float*)take((size_t)Nn * 1024 * 4);      // layer-1 scatter-sum
  unsigned short* agg2b = (unsigned short*)take((size_t)Nn * 512 * 2);
  unsigned short* xb    = (unsigned short*)take((size_t)Nn * 256 * 2);
  unsigned short* zxb   = (unsigned short*)take((size_t)Nn * 1024 * 2);
  int* pos  = (int*)take((size_t)Nn * 4);
  int* perm = (int*)take((size_t)E * 4);
  int* ssrc = (int*)take((size_t)E * 4);
  int* sdst = (int*)take((size_t)E * 4);

  long avail = (long)ws_size - (long)(p - (char*)d_ws);

  unsigned short* eas = nullptr;              // sorted bf16 edge_attr (optional)
  const long eas_bytes = (((long)E * 256 * 2) + 255) & ~255L;
  if (avail >= eas_bytes + 128 * 3072 + 1024) {
    eas = (unsigned short*)take((size_t)E * 256 * 2);
    avail -= eas_bytes;
  }
  long bandN = avail / 3072;  bandN &= ~127L;
  if (bandN > 50048) bandN = 50048;
  if (bandN < 128)   bandN = 128;
  unsigned short* H3 = (unsigned short*)take((size_t)bandN * 3072);

  const int mtE = (E + 127) / 128;

  hipMemsetAsync(cnt, 0, (size_t)Nn * 4, stream);
  fixcnt_k<<<(2 * E + 255) / 256, 256, 0, stream>>>(eraw, idx, cnt, E);
  scan_k<<<1, 1024, 0, stream>>>(cnt, pos, Nn);
  perm_k<<<(E + 255) / 256, 256, 0, stream>>>(idx, E, pos, perm, ssrc, sdst);
  // targeted zeroing of atomicAdd-target rows (replaces 205 MB memset)
  zb_k<<<mtE * 2, 256, 0, stream>>>(sdst, aggH, E, mtE);
  zc_k<<<104, 256, 0, stream>>>(cnt, aggH, Nn);
  cvt_f2b_k<<<(Nn * 64 + 255) / 256, 256, 0, stream>>>(x, xb, (long)Nn * 64);
  if (eas)
    cvt_eas_k<<<(int)(((long)E * 64 + 255) / 256), 256, 0, stream>>>(ea, perm,
                                                                     eas, E);
  cvt_w_k<<<(256 * 1024 + 255) / 256, 256, 0, stream>>>(W1, W1xt, 256, 1024);
  cvt_w_k<<<(256 * 1024 + 255) / 256, 256, 0, stream>>>(W1 + 256 * 1024, W1et,
                                                        256, 1024);
  cvt_w_k<<<(1024 * 512 + 255) / 256, 256, 0, stream>>>(W2, W2t, 1024, 512);
  cvt_w_k<<<(768 * 1536 + 255) / 256, 256, 0, stream>>>(W3, W3t, 768, 1536);
  cvt_w_k<<<(1536 * 256 + 255) / 256, 256, 0, stream>>>(W4, W4t, 1536, 256);

  // ZX: zxb = bf16(x @ W1x)   [x-half of layer 1, deduped to nodes]
  {
    const int mt = (Nn + 127) / 128, mtc = (mt + 7) / 8;
    gemm_k<5, 256, 1024, 8, false><<<mtc * 8 * 8, 256, 0, stream>>>(
        nullptr, xb, nullptr, nullptr, nullptr, nullptr, nullptr, nullptr,
        nullptr, nullptr, nullptr, W1xt, nullptr, nullptr, zxb, Nn, 0, mt, mtc);
  }

  // G1': edge layer-1 (ea half, K=256) + split-ZL zxb staging + run-merge
  {
    const int mt = mtE, mtc = (mt + 7) / 8;
    const int grid = mtc * 8 * 8;
    if (eas)
      gemm_k<1, 256, 1024, 8, true><<<grid, 256, 0, stream>>>(
          nullptr, nullptr, eas, ea, nullptr, nullptr, nullptr, zxb, perm,
          ssrc, sdst, W1et, b1, aggH, nullptr, E, 0, mt, mtc);
    else
      gemm_k<1, 256, 1024, 8, false><<<grid, 256, 0, stream>>>(
          nullptr, nullptr, nullptr, ea, nullptr, nullptr, nullptr, zxb, perm,
          ssrc, sdst, W1et, b1, aggH, nullptr, E, 0, mt, mtc);
  }

  // A2: agg2 = (aggH @ W2)/max(cnt,1) + (cnt>0)*b2   [normalize in epilogue]
  {
    const int mt = (Nn + 127) / 128, mtc = (mt + 7) / 8;
    gemm_k<2, 1024, 512, 4, false><<<mtc * 8 * 4, 256, 0, stream>>>(
        nullptr, nullptr, nullptr, nullptr, aggH, cnt, nullptr, nullptr,
        nullptr, nullptr, nullptr, W2t, b2, nullptr, agg2b, Nn, 0, mt, mtc);
  }

  // node MLP, banded over nodes
  for (long base = 0; base < Nn; base += bandN) {
    long rem = Nn - base;
    int mb = (int)(rem < bandN ? rem : bandN);
    int mt = (mb + 127) / 128, mtc = (mt + 7) / 8;
    gemm_k<3, 768, 1536, 12, false><<<mtc * 8 * 12, 256, 0, stream>>>(
        nullptr, xb, nullptr, nullptr, nullptr, nullptr, agg2b, nullptr,
        nullptr, nullptr, nullptr, W3t, b3, nullptr, H3, mb, (int)base, mt, mtc);
    gemm_k<4, 1536, 256, 2, false><<<mtc * 8 * 2, 256, 0, stream>>>(
        H3, nullptr, nullptr, nullptr, nullptr, nullptr, nullptr, nullptr,
        nullptr, nullptr, nullptr, W4t, b4, out, nullptr, mb, (int)base, mt, mtc);
  }
}